// Round 1
// baseline (277.752 us; speedup 1.0000x reference)
//
#include <hip/hip_runtime.h>
#include <hip/hip_bf16.h>

// Problem constants
static constexpr int BATCH = 16384;   // rows of x
static constexpr int DIM   = 1024;    // feature dim
static constexpr int NN    = 1024;    // 32*32 grid nodes
static constexpr int G     = 32;      // grid side

typedef _Float16 half8  __attribute__((ext_vector_type(8)));
typedef _Float16 half4v __attribute__((ext_vector_type(4)));
typedef float    f32x4  __attribute__((ext_vector_type(4)));

// ---------------------------------------------------------------------------
// Kernel 1: fp32 -> fp16 conversion of x (vectorized, memory-bound)
// ---------------------------------------------------------------------------
__global__ __launch_bounds__(256) void cvt_x_kernel(const float* __restrict__ X,
                                                    _Float16* __restrict__ Xh) {
    int i = blockIdx.x * 256 + threadIdx.x;   // one float4 per thread
    float4 v = ((const float4*)X)[i];
    half4v h;
    h[0] = (_Float16)v.x; h[1] = (_Float16)v.y;
    h[2] = (_Float16)v.z; h[3] = (_Float16)v.w;
    ((half4v*)Xh)[i] = h;
}

// ---------------------------------------------------------------------------
// Kernel 2: prep w -> fp16 copy, fp16 transpose, fp32 row norms
// One block per node n (1024 blocks x 256 threads)
// ---------------------------------------------------------------------------
__global__ __launch_bounds__(256) void prep_w_kernel(const float* __restrict__ W,
                                                     _Float16* __restrict__ Wh,
                                                     _Float16* __restrict__ WTh,
                                                     float* __restrict__ wsq) {
    int n = blockIdx.x;
    int t = threadIdx.x;
    float4 v = ((const float4*)(W + (size_t)n * DIM))[t];
    half4v h;
    h[0] = (_Float16)v.x; h[1] = (_Float16)v.y;
    h[2] = (_Float16)v.z; h[3] = (_Float16)v.w;
    ((half4v*)(Wh + (size_t)n * DIM))[t] = h;
    // transpose: WTh[d][n] = w[n][d]  (scattered 2B stores; only 2MB total)
    int d0 = t * 4;
    WTh[(size_t)(d0 + 0) * NN + n] = h[0];
    WTh[(size_t)(d0 + 1) * NN + n] = h[1];
    WTh[(size_t)(d0 + 2) * NN + n] = h[2];
    WTh[(size_t)(d0 + 3) * NN + n] = h[3];
    float ss = v.x * v.x + v.y * v.y + v.z * v.z + v.w * v.w;
    __shared__ float red[256];
    red[t] = ss;
    __syncthreads();
    for (int s = 128; s > 0; s >>= 1) {
        if (t < s) red[t] += red[t + s];
        __syncthreads();
    }
    if (t == 0) wsq[n] = red[0];
}

// ---------------------------------------------------------------------------
// GEMM: C[M,N] = A[M,K] * B[N,K]^T   (both operands fp16, K-contiguous rows)
// 128x128 block tile, BK=32, 4 waves (2x2), 64x64 per wave, mfma 16x16x32 f16.
// EPI==1: C = 2*acc - wsq[col]  (distance-logit epilogue)
// EPI==0: C = acc               (reconstruction)
// ---------------------------------------------------------------------------
template <int EPI>
__global__ __launch_bounds__(256) void gemm_bt_kernel(const _Float16* __restrict__ A,
                                                      const _Float16* __restrict__ B,
                                                      float* __restrict__ C,
                                                      const float* __restrict__ wsq,
                                                      int M, int N, int K) {
    __shared__ __align__(16) _Float16 As[128 * 32];
    __shared__ __align__(16) _Float16 Bs[128 * 32];

    const int t  = threadIdx.x;
    const int l  = t & 63;        // lane in wave
    const int wv = t >> 6;        // wave id 0..3
    const int bm = blockIdx.y * 128;
    const int bn = blockIdx.x * 128;
    const int wm = (wv >> 1) * 64;    // wave row offset within tile
    const int wn = (wv & 1) * 64;     // wave col offset within tile

    // staging geometry: each wave stages 32 rows of A and 32 rows of B per k-iter
    // via global_load_lds width 16 (wave-uniform LDS base + lane*16 bytes)
    const int srow = (l >> 2);        // 0..15: row within 16-row segment
    const int skk  = (l & 3) * 8;     // 0/8/16/24: k offset (halfs)

    auto stage = [&](int k0) {
#pragma unroll
        for (int j = 0; j < 2; ++j) {
            int rbase = wv * 32 + j * 16;                 // wave-uniform
            const _Float16* gA = A + (size_t)(bm + rbase + srow) * K + k0 + skk;
            __builtin_amdgcn_global_load_lds(
                (const __attribute__((address_space(1))) void*)gA,
                (__attribute__((address_space(3))) void*)(As + rbase * 32), 16, 0, 0);
            const _Float16* gB = B + (size_t)(bn + rbase + srow) * K + k0 + skk;
            __builtin_amdgcn_global_load_lds(
                (const __attribute__((address_space(1))) void*)gB,
                (__attribute__((address_space(3))) void*)(Bs + rbase * 32), 16, 0, 0);
        }
    };

    f32x4 acc[4][4] = {};

    stage(0);
    for (int kt = 0; kt < K; kt += 32) {
        __syncthreads();   // compiler emits vmcnt(0) drain before barrier
        const int kq   = (l >> 4) * 8;      // quad*8: k offset of this lane's frag
        const int mrow = wm + (l & 15);
        const int ncol = wn + (l & 15);
        half8 af[4], bf[4];
#pragma unroll
        for (int mi = 0; mi < 4; ++mi)
            af[mi] = *(const half8*)(As + (mrow + mi * 16) * 32 + kq);
#pragma unroll
        for (int ni = 0; ni < 4; ++ni)
            bf[ni] = *(const half8*)(Bs + (ncol + ni * 16) * 32 + kq);
#pragma unroll
        for (int mi = 0; mi < 4; ++mi)
#pragma unroll
            for (int ni = 0; ni < 4; ++ni)
                acc[mi][ni] = __builtin_amdgcn_mfma_f32_16x16x32_f16(
                    af[mi], bf[ni], acc[mi][ni], 0, 0, 0);
        __syncthreads();
        if (kt + 32 < K) stage(kt + 32);
    }

    // epilogue: C/D layout col = lane&15, row = (lane>>4)*4 + r
#pragma unroll
    for (int mi = 0; mi < 4; ++mi) {
        const int rbase = bm + wm + mi * 16 + (l >> 4) * 4;
#pragma unroll
        for (int ni = 0; ni < 4; ++ni) {
            const int col = bn + wn + ni * 16 + (l & 15);
            float wq = (EPI == 1) ? wsq[col] : 0.f;
#pragma unroll
            for (int r = 0; r < 4; ++r) {
                float v = acc[mi][ni][r];
                if (EPI == 1) v = 2.f * v - wq;
                C[(size_t)(rbase + r) * N + col] = v;
            }
        }
    }
}

// ---------------------------------------------------------------------------
// Kernel 4: dual-axis softmax + combine + normalize; output fp16
// One block (256 threads) per batch row b. Grid is 32x32: n = g1*32 + g2.
// s1 = softmax over axis 1 (g1, stride 32)  -> stats indexed by g2
// s2 = softmax over axis 2 (g2, contiguous) -> stats indexed by g1
// ---------------------------------------------------------------------------
__global__ __launch_bounds__(256) void softmax_kernel(const float* __restrict__ L,
                                                      _Float16* __restrict__ Ch) {
    const int b = blockIdx.x;
    const int t = threadIdx.x;
    __shared__ float sl[1024];
    __shared__ float rmax[G], rsum[G], cmax[G], csum[G];
    __shared__ float red[256];

    float4 v = ((const float4*)(L + (size_t)b * NN))[t];
    sl[t * 4 + 0] = v.x; sl[t * 4 + 1] = v.y;
    sl[t * 4 + 2] = v.z; sl[t * 4 + 3] = v.w;
    __syncthreads();

    if (t < G) {            // row stats: fixed g1 = t, over g2 (contiguous)
        float m = -1e30f;
        for (int j = 0; j < G; ++j) m = fmaxf(m, sl[t * G + j]);
        float s = 0.f;
        for (int j = 0; j < G; ++j) s += __expf(sl[t * G + j] - m);
        rmax[t] = m; rsum[t] = s;
    } else if (t < 2 * G) { // col stats: fixed g2 = t-32, over g1 (stride 32)
        int g2 = t - G;
        float m = -1e30f;
        for (int j = 0; j < G; ++j) m = fmaxf(m, sl[j * G + g2]);
        float s = 0.f;
        for (int j = 0; j < G; ++j) s += __expf(sl[j * G + g2] - m);
        cmax[g2] = m; csum[g2] = s;
    }
    __syncthreads();

    float c[4];
    float mysum = 0.f;
#pragma unroll
    for (int i = 0; i < 4; ++i) {
        int n  = t * 4 + i;
        int g1 = n >> 5;
        int g2 = n & 31;
        float lv = sl[n];
        float s1 = __expf(lv - cmax[g2]) / csum[g2];   // softmax over axis 1
        float s2 = __expf(lv - rmax[g1]) / rsum[g1];   // softmax over axis 2
        c[i] = s1 * s2;
        mysum += c[i];
    }
    red[t] = mysum;
    __syncthreads();
    for (int s = 128; s > 0; s >>= 1) {
        if (t < s) red[t] += red[t + s];
        __syncthreads();
    }
    float inv = 1.f / (red[0] + 1e-8f);
    half4v h;
#pragma unroll
    for (int i = 0; i < 4; ++i) h[i] = (_Float16)(c[i] * inv);
    ((half4v*)(Ch + (size_t)b * NN))[t] = h;
}

// ---------------------------------------------------------------------------
extern "C" void kernel_launch(void* const* d_in, const int* in_sizes, int n_in,
                              void* d_out, int out_size, void* d_ws, size_t ws_size,
                              hipStream_t stream) {
    const float* x = (const float*)d_in[0];        // [16384, 1024] fp32
    const float* w = (const float*)d_in[1];        // [32, 32, 1024] fp32
    float* out = (float*)d_out;                    // [16384, 1024] fp32

    char* ws = (char*)d_ws;
    size_t off = 0;
    _Float16* xh  = (_Float16*)(ws + off); off += (size_t)BATCH * DIM * 2;   // 32 MB
    _Float16* ch  = (_Float16*)(ws + off); off += (size_t)BATCH * NN * 2;    // 32 MB
    float*    L   = (float*)   (ws + off); off += (size_t)BATCH * NN * 4;    // 64 MB
    _Float16* wh  = (_Float16*)(ws + off); off += (size_t)NN * DIM * 2;      // 2 MB
    _Float16* wth = (_Float16*)(ws + off); off += (size_t)DIM * NN * 2;      // 2 MB
    float*    wsq = (float*)   (ws + off); off += (size_t)NN * 4;

    // 1. x -> fp16
    cvt_x_kernel<<<(BATCH * DIM / 4) / 256, 256, 0, stream>>>(x, xh);
    // 2. w -> fp16 (+ transpose + row norms)
    prep_w_kernel<<<NN, 256, 0, stream>>>(w, wh, wth, wsq);
    // 3. L = 2 * (x @ w^T) - ||w||^2   (softmax-equivalent logits; ||x||^2 cancels)
    gemm_bt_kernel<1><<<dim3(NN / 128, BATCH / 128), 256, 0, stream>>>(
        xh, wh, L, wsq, BATCH, NN, DIM);
    // 4. dual softmax + combine + normalize -> fp16 weights
    softmax_kernel<<<BATCH, 256, 0, stream>>>(L, ch);
    // 5. recon = combined @ w   (B operand = w^T so rows are K-contiguous)
    gemm_bt_kernel<0><<<dim3(DIM / 128, BATCH / 128), 256, 0, stream>>>(
        ch, wth, out, nullptr, BATCH, DIM, NN);
}

// Round 2
// 253.432 us; speedup vs baseline: 1.0960x; 1.0960x over previous
//
#include <hip/hip_runtime.h>
#include <hip/hip_bf16.h>

// Problem constants
static constexpr int BATCH = 16384;   // rows of x
static constexpr int DIM   = 1024;    // feature dim
static constexpr int NN    = 1024;    // 32*32 grid nodes
static constexpr int G     = 32;      // grid side

typedef _Float16 half8  __attribute__((ext_vector_type(8)));
typedef _Float16 half4v __attribute__((ext_vector_type(4)));
typedef float    f32x4  __attribute__((ext_vector_type(4)));

// ---------------------------------------------------------------------------
// Kernel 1: fp32 -> fp16 conversion of x (vectorized, memory-bound)
// ---------------------------------------------------------------------------
__global__ __launch_bounds__(256) void cvt_x_kernel(const float* __restrict__ X,
                                                    _Float16* __restrict__ Xh) {
    int i = blockIdx.x * 256 + threadIdx.x;   // one float4 per thread
    float4 v = ((const float4*)X)[i];
    half4v h;
    h[0] = (_Float16)v.x; h[1] = (_Float16)v.y;
    h[2] = (_Float16)v.z; h[3] = (_Float16)v.w;
    ((half4v*)Xh)[i] = h;
}

// ---------------------------------------------------------------------------
// Kernel 2: prep w -> fp16 copy, fp16 transpose, fp32 row norms
// ---------------------------------------------------------------------------
__global__ __launch_bounds__(256) void prep_w_kernel(const float* __restrict__ W,
                                                     _Float16* __restrict__ Wh,
                                                     _Float16* __restrict__ WTh,
                                                     float* __restrict__ wsq) {
    int n = blockIdx.x;
    int t = threadIdx.x;
    float4 v = ((const float4*)(W + (size_t)n * DIM))[t];
    half4v h;
    h[0] = (_Float16)v.x; h[1] = (_Float16)v.y;
    h[2] = (_Float16)v.z; h[3] = (_Float16)v.w;
    ((half4v*)(Wh + (size_t)n * DIM))[t] = h;
    int d0 = t * 4;
    WTh[(size_t)(d0 + 0) * NN + n] = h[0];
    WTh[(size_t)(d0 + 1) * NN + n] = h[1];
    WTh[(size_t)(d0 + 2) * NN + n] = h[2];
    WTh[(size_t)(d0 + 3) * NN + n] = h[3];
    float ss = v.x * v.x + v.y * v.y + v.z * v.z + v.w * v.w;
    __shared__ float red[256];
    red[t] = ss;
    __syncthreads();
    for (int s = 128; s > 0; s >>= 1) {
        if (t < s) red[t] += red[t + s];
        __syncthreads();
    }
    if (t == 0) wsq[n] = red[0];
}

// ---------------------------------------------------------------------------
// GEMM: C[M,N] = A[M,K] * B[N,K]^T   (fp16 operands, K-contiguous rows)
// 128x128 tile, BK=32, 4 waves, 64x64/wave, mfma 16x16x32 f16.
// LDS layout XOR-swizzled: k-chunk c of row r lives at slot c ^ ((r>>1)&3)
// (8-way bank conflict -> 2-way/free). XCD-aware tile swizzle: xcd = lid&7
// owns a contiguous strip of M-tiles so each XCD's L2 sees 1/8 of A.
// EPI==1: C = 2*acc - wsq[col]; EPI==0: C = acc.
// ---------------------------------------------------------------------------
template <int EPI>
__global__ __launch_bounds__(256) void gemm_bt_kernel(const _Float16* __restrict__ A,
                                                      const _Float16* __restrict__ B,
                                                      float* __restrict__ C,
                                                      const float* __restrict__ wsq,
                                                      int M, int N, int K) {
    __shared__ __align__(16) _Float16 As[128 * 32];
    __shared__ __align__(16) _Float16 Bs[128 * 32];

    const int t  = threadIdx.x;
    const int l  = t & 63;
    const int wv = t >> 6;

    // XCD-aware tile swizzle (heuristic: consecutive blocks round-robin XCDs)
    const int NT = N >> 7;            // 8 n-tiles
    const int MT = M >> 7;            // 128 m-tiles
    const int lid  = blockIdx.x;
    const int xcd  = lid & 7;
    const int i    = lid >> 3;
    const int bn   = (i % NT) * 128;
    const int bm   = (xcd * (MT >> 3) + i / NT) * 128;

    const int wm = (wv >> 1) * 64;
    const int wn = (wv & 1) * 64;

    // staging: per call, 16 rows x 4 slots of 16B. LDS dest is fixed
    // lane-contiguous; permute the SOURCE k-chunk to realize the swizzle.
    const int srow = (l >> 2);                               // 0..15
    const int skk  = (((l & 3) ^ ((srow >> 1) & 3)) * 8);    // swizzled k-chunk

    auto stage = [&](int k0) {
#pragma unroll
        for (int j = 0; j < 2; ++j) {
            int rbase = wv * 32 + j * 16;
            const _Float16* gA = A + (size_t)(bm + rbase + srow) * K + k0 + skk;
            __builtin_amdgcn_global_load_lds(
                (const __attribute__((address_space(1))) void*)gA,
                (__attribute__((address_space(3))) void*)(As + rbase * 32), 16, 0, 0);
            const _Float16* gB = B + (size_t)(bn + rbase + srow) * K + k0 + skk;
            __builtin_amdgcn_global_load_lds(
                (const __attribute__((address_space(1))) void*)gB,
                (__attribute__((address_space(3))) void*)(Bs + rbase * 32), 16, 0, 0);
        }
    };

    f32x4 acc[4][4] = {};

    stage(0);
    const int xr    = ((l & 15) >> 1) & 3;            // read-side xor (mi-invariant)
    const int kqs   = (((l >> 4) ^ xr) * 8);          // swizzled k offset in halfs
    const int mrow  = wm + (l & 15);
    const int ncol  = wn + (l & 15);

    for (int kt = 0; kt < K; kt += 32) {
        __syncthreads();
        half8 af[4], bf[4];
#pragma unroll
        for (int mi = 0; mi < 4; ++mi)
            af[mi] = *(const half8*)(As + (mrow + mi * 16) * 32 + kqs);
#pragma unroll
        for (int ni = 0; ni < 4; ++ni)
            bf[ni] = *(const half8*)(Bs + (ncol + ni * 16) * 32 + kqs);
#pragma unroll
        for (int mi = 0; mi < 4; ++mi)
#pragma unroll
            for (int ni = 0; ni < 4; ++ni)
                acc[mi][ni] = __builtin_amdgcn_mfma_f32_16x16x32_f16(
                    af[mi], bf[ni], acc[mi][ni], 0, 0, 0);
        __syncthreads();
        if (kt + 32 < K) stage(kt + 32);
    }

    // epilogue: C/D layout col = lane&15, row = (lane>>4)*4 + r
#pragma unroll
    for (int mi = 0; mi < 4; ++mi) {
        const int rbase = bm + wm + mi * 16 + (l >> 4) * 4;
#pragma unroll
        for (int ni = 0; ni < 4; ++ni) {
            const int col = bn + wn + ni * 16 + (l & 15);
            float wq = (EPI == 1) ? wsq[col] : 0.f;
#pragma unroll
            for (int r = 0; r < 4; ++r) {
                float v = acc[mi][ni][r];
                if (EPI == 1) v = 2.f * v - wq;
                C[(size_t)(rbase + r) * N + col] = v;
            }
        }
    }
}

// ---------------------------------------------------------------------------
// Kernel 4: dual-axis softmax + combine + normalize; output fp16.
// One block per batch row. Stats loops are LDS-conflict-free (skewed reads),
// row stats in wave 0, col stats in wave 1 (parallel, no intra-wave split).
// combine uses one exp: s1*s2 = exp(2lv - cmax - rmax) * cinv * rinv.
// ---------------------------------------------------------------------------
__global__ __launch_bounds__(256) void softmax_kernel(const float* __restrict__ L,
                                                      _Float16* __restrict__ Ch) {
    const int b = blockIdx.x;
    const int t = threadIdx.x;
    __shared__ float sl[1024];
    __shared__ float rmax[G], rinv[G], cmax[G], cinv[G];
    __shared__ float wsum[4];

    float4 v = ((const float4*)(L + (size_t)b * NN))[t];
    sl[t * 4 + 0] = v.x; sl[t * 4 + 1] = v.y;
    sl[t * 4 + 2] = v.z; sl[t * 4 + 3] = v.w;
    __syncthreads();

    if (t < G) {
        // row stats: fixed g1 = t, over contiguous g2; skewed -> bank (j+t)&31
        float m = -1e30f;
#pragma unroll
        for (int j = 0; j < G; ++j) m = fmaxf(m, sl[t * G + ((j + t) & 31)]);
        float s = 0.f;
#pragma unroll
        for (int j = 0; j < G; ++j) s += __expf(sl[t * G + ((j + t) & 31)] - m);
        rmax[t] = m; rinv[t] = 1.f / s;
    } else if (t >= 64 && t < 64 + G) {
        // col stats: fixed g2, over g1 (stride 32) — naturally conflict-free
        int g2 = t - 64;
        float m = -1e30f;
#pragma unroll
        for (int j = 0; j < G; ++j) m = fmaxf(m, sl[j * G + g2]);
        float s = 0.f;
#pragma unroll
        for (int j = 0; j < G; ++j) s += __expf(sl[j * G + g2] - m);
        cmax[g2] = m; cinv[g2] = 1.f / s;
    }
    __syncthreads();

    float c[4];
    float mysum = 0.f;
#pragma unroll
    for (int i = 0; i < 4; ++i) {
        int n  = t * 4 + i;
        int g1 = n >> 5;
        int g2 = n & 31;
        float lv = sl[n];
        c[i] = __expf(2.f * lv - cmax[g2] - rmax[g1]) * cinv[g2] * rinv[g1];
        mysum += c[i];
    }
#pragma unroll
    for (int o = 32; o > 0; o >>= 1) mysum += __shfl_xor(mysum, o, 64);
    if ((t & 63) == 0) wsum[t >> 6] = mysum;
    __syncthreads();
    float inv = 1.f / (wsum[0] + wsum[1] + wsum[2] + wsum[3] + 1e-8f);
    half4v h;
#pragma unroll
    for (int i = 0; i < 4; ++i) h[i] = (_Float16)(c[i] * inv);
    ((half4v*)(Ch + (size_t)b * NN))[t] = h;
}

// ---------------------------------------------------------------------------
extern "C" void kernel_launch(void* const* d_in, const int* in_sizes, int n_in,
                              void* d_out, int out_size, void* d_ws, size_t ws_size,
                              hipStream_t stream) {
    const float* x = (const float*)d_in[0];        // [16384, 1024] fp32
    const float* w = (const float*)d_in[1];        // [32, 32, 1024] fp32
    float* out = (float*)d_out;                    // [16384, 1024] fp32

    char* ws = (char*)d_ws;
    size_t off = 0;
    _Float16* xh  = (_Float16*)(ws + off); off += (size_t)BATCH * DIM * 2;   // 32 MB
    _Float16* ch  = (_Float16*)(ws + off); off += (size_t)BATCH * NN * 2;    // 32 MB
    float*    L   = (float*)   (ws + off); off += (size_t)BATCH * NN * 4;    // 64 MB
    _Float16* wh  = (_Float16*)(ws + off); off += (size_t)NN * DIM * 2;      // 2 MB
    _Float16* wth = (_Float16*)(ws + off); off += (size_t)DIM * NN * 2;      // 2 MB
    float*    wsq = (float*)   (ws + off); off += (size_t)NN * 4;

    // 1. x -> fp16
    cvt_x_kernel<<<(BATCH * DIM / 4) / 256, 256, 0, stream>>>(x, xh);
    // 2. w -> fp16 (+ transpose + row norms)
    prep_w_kernel<<<NN, 256, 0, stream>>>(w, wh, wth, wsq);
    // 3. L = 2 * (x @ w^T) - ||w||^2
    gemm_bt_kernel<1><<<(BATCH / 128) * (NN / 128), 256, 0, stream>>>(
        xh, wh, L, wsq, BATCH, NN, DIM);
    // 4. dual softmax + combine + normalize -> fp16 weights
    softmax_kernel<<<BATCH, 256, 0, stream>>>(L, ch);
    // 5. recon = combined @ w
    gemm_bt_kernel<0><<<(BATCH / 128) * (DIM / 128), 256, 0, stream>>>(
        ch, wth, out, nullptr, BATCH, DIM, NN);
}

// Round 3
// 247.840 us; speedup vs baseline: 1.1207x; 1.0226x over previous
//
#include <hip/hip_runtime.h>
#include <hip/hip_bf16.h>

// Problem constants
static constexpr int BATCH = 16384;   // rows of x
static constexpr int DIM   = 1024;    // feature dim
static constexpr int NN    = 1024;    // 32*32 grid nodes
static constexpr int G     = 32;      // grid side

typedef _Float16 half8  __attribute__((ext_vector_type(8)));
typedef _Float16 half4v __attribute__((ext_vector_type(4)));
typedef float    f32x4  __attribute__((ext_vector_type(4)));

// ---------------------------------------------------------------------------
// prep A: w -> fp16 copy + coalesced fp16 transpose via 64x64 LDS tile
// grid 256 blocks (16 x 16 tiles), 256 threads
// ---------------------------------------------------------------------------
__global__ __launch_bounds__(256) void transpose_w_kernel(const float* __restrict__ W,
                                                          _Float16* __restrict__ Wh,
                                                          _Float16* __restrict__ WTh) {
    __shared__ _Float16 tile[64][72];   // [d'][n'], +8 pad
    const int t  = threadIdx.x;
    const int n0 = (blockIdx.x & 15) * 64;
    const int d0 = (blockIdx.x >> 4) * 64;
#pragma unroll
    for (int p = 0; p < 4; ++p) {
        int n = n0 + p * 16 + (t >> 4);
        int d = d0 + (t & 15) * 4;
        float4 v = *(const float4*)(W + (size_t)n * DIM + d);
        half4v h;
        h[0] = (_Float16)v.x; h[1] = (_Float16)v.y;
        h[2] = (_Float16)v.z; h[3] = (_Float16)v.w;
        *(half4v*)(Wh + (size_t)n * DIM + d) = h;
#pragma unroll
        for (int k = 0; k < 4; ++k)
            tile[(t & 15) * 4 + k][p * 16 + (t >> 4)] = h[k];
    }
    __syncthreads();
#pragma unroll
    for (int p = 0; p < 4; ++p) {
        int dp = p * 16 + (t >> 4);
        int nc = (t & 15) * 4;
        half4v hv = *(const half4v*)&tile[dp][nc];
        *(half4v*)(WTh + (size_t)(d0 + dp) * NN + n0 + nc) = hv;
    }
}

// ---------------------------------------------------------------------------
// prep B: wsq[n] = ||w_n||^2  (1024 blocks x 256 threads, coalesced)
// ---------------------------------------------------------------------------
__global__ __launch_bounds__(256) void wsq_kernel(const float* __restrict__ W,
                                                  float* __restrict__ wsq) {
    const int n = blockIdx.x;
    const int t = threadIdx.x;
    float4 v = *(const float4*)(W + (size_t)n * DIM + 4 * t);
    float ss = v.x * v.x + v.y * v.y + v.z * v.z + v.w * v.w;
#pragma unroll
    for (int o = 32; o > 0; o >>= 1) ss += __shfl_xor(ss, o, 64);
    __shared__ float red[4];
    if ((t & 63) == 0) red[t >> 6] = ss;
    __syncthreads();
    if (t == 0) wsq[n] = red[0] + red[1] + red[2] + red[3];
}

// ---------------------------------------------------------------------------
// GEMM: C[M,N] = A[M,K] * B[N,K]^T.  BK=64, 128x128 tile, 4 waves, 64x64/wave,
// mfma 16x16x32 f16.  A dtype templated: float (converted in-reg) or fp16.
// XOR-swizzled LDS (16B-chunk granularity) -> conflict-free ds_read_b128.
// XCD-aware tile swizzle.  EPI==1: C = 2*acc - wsq[col]; EPI==0: C = acc.
// ---------------------------------------------------------------------------
template <typename AT, int EPI>
__global__ __launch_bounds__(256) void gemm_bt_kernel(const AT* __restrict__ A,
                                                      const _Float16* __restrict__ B,
                                                      float* __restrict__ C,
                                                      const float* __restrict__ wsq,
                                                      int M, int N, int K) {
    constexpr bool AF32 = sizeof(AT) == 4;
    // A rows: 64 elems of sizeof(AT); B rows: 64 halfs
    __shared__ __align__(16) AT       As[128 * 64];
    __shared__ __align__(16) _Float16 Bs[128 * 64];

    const int t  = threadIdx.x;
    const int l  = t & 63;
    const int wv = t >> 6;

    // XCD-aware tile swizzle
    const int NT  = N >> 7;
    const int MT  = M >> 7;
    const int lid = blockIdx.x;
    const int xcd = lid & 7;
    const int i0  = lid >> 3;
    const int bn  = (i0 % NT) * 128;
    const int bm  = (xcd * (MT >> 3) + i0 / NT) * 128;

    const int wm = (wv >> 1) * 64;
    const int wn = (wv & 1) * 64;

    auto stage = [&](int k0) {
        if constexpr (AF32) {
            // A fp32: row = 256B = 16 chunks; 4 rows per call; 8 calls/wave
#pragma unroll
            for (int j = 0; j < 8; ++j) {
                int rbase = wv * 32 + j * 4;
                int row   = rbase + (l >> 4);
                int c     = (l & 15) ^ (row & 15);
                const float* gA = (const float*)A + (size_t)(bm + row) * K + k0 + c * 4;
                __builtin_amdgcn_global_load_lds(
                    (const __attribute__((address_space(1))) void*)gA,
                    (__attribute__((address_space(3))) void*)((float*)As + rbase * 64),
                    16, 0, 0);
            }
        } else {
            // A fp16: row = 128B = 8 chunks; 8 rows per call; 4 calls/wave
#pragma unroll
            for (int j = 0; j < 4; ++j) {
                int rbase = wv * 32 + j * 8;
                int row   = rbase + (l >> 3);
                int c     = (l & 7) ^ (row & 7);
                const _Float16* gA = (const _Float16*)A + (size_t)(bm + row) * K + k0 + c * 8;
                __builtin_amdgcn_global_load_lds(
                    (const __attribute__((address_space(1))) void*)gA,
                    (__attribute__((address_space(3))) void*)((_Float16*)As + rbase * 64),
                    16, 0, 0);
            }
        }
        // B fp16
#pragma unroll
        for (int j = 0; j < 4; ++j) {
            int rbase = wv * 32 + j * 8;
            int row   = rbase + (l >> 3);
            int c     = (l & 7) ^ (row & 7);
            const _Float16* gB = B + (size_t)(bn + row) * K + k0 + c * 8;
            __builtin_amdgcn_global_load_lds(
                (const __attribute__((address_space(1))) void*)gB,
                (__attribute__((address_space(3))) void*)(Bs + rbase * 64),
                16, 0, 0);
        }
    };

    f32x4 acc[4][4] = {};
    stage(0);

    for (int kt = 0; kt < K; kt += 64) {
        __syncthreads();
#pragma unroll
        for (int sub = 0; sub < 2; ++sub) {
            half8 af[4], bf[4];
#pragma unroll
            for (int mi = 0; mi < 4; ++mi) {
                if constexpr (AF32) {
                    const float* pa = (const float*)As + (wm + (l & 15) + mi * 16) * 64;
                    int cpair = sub * 8 + (l >> 4) * 2;
                    f32x4 lo = *(const f32x4*)(pa + ((cpair     ) ^ (l & 15)) * 4);
                    f32x4 hi = *(const f32x4*)(pa + ((cpair + 1) ^ (l & 15)) * 4);
#pragma unroll
                    for (int q = 0; q < 4; ++q) {
                        af[mi][q]     = (_Float16)lo[q];
                        af[mi][4 + q] = (_Float16)hi[q];
                    }
                } else {
                    const _Float16* pa = (const _Float16*)As + (wm + (l & 15) + mi * 16) * 64;
                    int c = sub * 4 + (l >> 4);
                    af[mi] = *(const half8*)(pa + (c ^ (l & 7)) * 8);
                }
            }
#pragma unroll
            for (int ni = 0; ni < 4; ++ni) {
                const _Float16* pb = Bs + (wn + (l & 15) + ni * 16) * 64;
                int c = sub * 4 + (l >> 4);
                bf[ni] = *(const half8*)(pb + (c ^ (l & 7)) * 8);
            }
#pragma unroll
            for (int mi = 0; mi < 4; ++mi)
#pragma unroll
                for (int ni = 0; ni < 4; ++ni)
                    acc[mi][ni] = __builtin_amdgcn_mfma_f32_16x16x32_f16(
                        af[mi], bf[ni], acc[mi][ni], 0, 0, 0);
        }
        __syncthreads();
        if (kt + 64 < K) stage(kt + 64);
    }

    // epilogue: C/D layout col = lane&15, row = (lane>>4)*4 + r
#pragma unroll
    for (int mi = 0; mi < 4; ++mi) {
        const int rbase = bm + wm + mi * 16 + (l >> 4) * 4;
#pragma unroll
        for (int ni = 0; ni < 4; ++ni) {
            const int col = bn + wn + ni * 16 + (l & 15);
            float wq = (EPI == 1) ? wsq[col] : 0.f;
#pragma unroll
            for (int r = 0; r < 4; ++r) {
                float v = acc[mi][ni][r];
                if (EPI == 1) v = 2.f * v - wq;
                C[(size_t)(rbase + r) * N + col] = v;
            }
        }
    }
}

// ---------------------------------------------------------------------------
// dual-axis softmax + combine + normalize; wave-per-row, register-only.
// Element map: lane l, quarter i, slot j -> n = i*256 + 4*l + j,
//   g1 = i*8 + (l>>3)  (varies: i in-lane, l>>3 via shfl {8,16,32})
//   g2 = 4*(l&7) + j   (varies: j in-lane, l&7 via shfl {1,2,4})
// s2-softmax (axis 2, over g2): reduce over {j, l&7};
// s1-softmax (axis 1, over g1): reduce over {i, l>>3}.
// ---------------------------------------------------------------------------
__global__ __launch_bounds__(256) void softmax_kernel(const float* __restrict__ L,
                                                      _Float16* __restrict__ Ch) {
    const int l  = threadIdx.x & 63;
    const int wv = threadIdx.x >> 6;
    const int b  = blockIdx.x * 4 + wv;

    const f32x4* Lr = (const f32x4*)(L + (size_t)b * NN);
    f32x4 v[4];
#pragma unroll
    for (int i = 0; i < 4; ++i) v[i] = Lr[i * 64 + l];

    float er[4][4], ec[4][4];
    float rinv[4];
    // s2 stats: per (i, l>>3) row of 32 contiguous elems
#pragma unroll
    for (int i = 0; i < 4; ++i) {
        float m = fmaxf(fmaxf(v[i][0], v[i][1]), fmaxf(v[i][2], v[i][3]));
        m = fmaxf(m, __shfl_xor(m, 1, 64));
        m = fmaxf(m, __shfl_xor(m, 2, 64));
        m = fmaxf(m, __shfl_xor(m, 4, 64));
        float s = 0.f;
#pragma unroll
        for (int j = 0; j < 4; ++j) { er[i][j] = __expf(v[i][j] - m); s += er[i][j]; }
        s += __shfl_xor(s, 1, 64);
        s += __shfl_xor(s, 2, 64);
        s += __shfl_xor(s, 4, 64);
        rinv[i] = 1.f / s;
    }
    // s1 stats: per (j, l&7) column of 32 stride-32 elems
#pragma unroll
    for (int j = 0; j < 4; ++j) {
        float m = fmaxf(fmaxf(v[0][j], v[1][j]), fmaxf(v[2][j], v[3][j]));
        m = fmaxf(m, __shfl_xor(m, 8, 64));
        m = fmaxf(m, __shfl_xor(m, 16, 64));
        m = fmaxf(m, __shfl_xor(m, 32, 64));
        float s = 0.f;
#pragma unroll
        for (int i = 0; i < 4; ++i) { ec[i][j] = __expf(v[i][j] - m); s += ec[i][j]; }
        s += __shfl_xor(s, 8, 64);
        s += __shfl_xor(s, 16, 64);
        s += __shfl_xor(s, 32, 64);
        float ci = 1.f / s;
#pragma unroll
        for (int i = 0; i < 4; ++i) ec[i][j] *= ci;
    }
    // combine + global normalize
    float c[4][4];
    float tot = 0.f;
#pragma unroll
    for (int i = 0; i < 4; ++i)
#pragma unroll
        for (int j = 0; j < 4; ++j) {
            c[i][j] = er[i][j] * rinv[i] * ec[i][j];
            tot += c[i][j];
        }
#pragma unroll
    for (int o = 32; o > 0; o >>= 1) tot += __shfl_xor(tot, o, 64);
    float inv = 1.f / (tot + 1e-8f);
#pragma unroll
    for (int i = 0; i < 4; ++i) {
        half4v h;
#pragma unroll
        for (int j = 0; j < 4; ++j) h[j] = (_Float16)(c[i][j] * inv);
        ((half4v*)(Ch + (size_t)b * NN))[i * 64 + l] = h;
    }
}

// ---------------------------------------------------------------------------
extern "C" void kernel_launch(void* const* d_in, const int* in_sizes, int n_in,
                              void* d_out, int out_size, void* d_ws, size_t ws_size,
                              hipStream_t stream) {
    const float* x = (const float*)d_in[0];        // [16384, 1024] fp32
    const float* w = (const float*)d_in[1];        // [32, 32, 1024] fp32
    float* out = (float*)d_out;                    // [16384, 1024] fp32

    char* ws = (char*)d_ws;
    size_t off = 0;
    _Float16* ch  = (_Float16*)(ws + off); off += (size_t)BATCH * NN * 2;    // 32 MB
    float*    L   = (float*)   (ws + off); off += (size_t)BATCH * NN * 4;    // 64 MB
    _Float16* wh  = (_Float16*)(ws + off); off += (size_t)NN * DIM * 2;      // 2 MB
    _Float16* wth = (_Float16*)(ws + off); off += (size_t)DIM * NN * 2;      // 2 MB
    float*    wsq = (float*)   (ws + off); off += (size_t)NN * 4;

    // 1. w -> fp16 + fp16 transpose (coalesced)
    transpose_w_kernel<<<256, 256, 0, stream>>>(w, wh, wth);
    // 2. wsq
    wsq_kernel<<<NN, 256, 0, stream>>>(w, wsq);
    // 3. L = 2 * (x @ w^T) - ||w||^2   (x staged fp32, converted in-reg)
    gemm_bt_kernel<float, 1><<<(BATCH / 128) * (NN / 128), 256, 0, stream>>>(
        x, wh, L, wsq, BATCH, NN, DIM);
    // 4. dual softmax + combine + normalize -> fp16 weights
    softmax_kernel<<<BATCH / 4, 256, 0, stream>>>(L, ch);
    // 5. recon = combined @ w
    gemm_bt_kernel<_Float16, 0><<<(BATCH / 128) * (DIM / 128), 256, 0, stream>>>(
        ch, wth, out, nullptr, BATCH, DIM, NN);
}